// Round 1
// baseline (152.187 us; speedup 1.0000x reference)
//
#include <hip/hip_runtime.h>

namespace {

constexpr int JN = 21;   // joints
constexpr int BN = 20;   // bones
constexpr float F_F  = 512.0f;
constexpr float PX_F = 512.0f;
constexpr float PY_F = 288.0f;
constexpr float EPS_F = 1e-8f;

// weights folded with per-loss divisors
constexpr float WPROJ   = 0.25f / (2.0f * 21.0f);
constexpr float WLIFT   = 0.25f / (3.0f * 21.0f);
constexpr float WBONE   = 0.25f / 20.0f;
constexpr float WSMOOTH = 0.25f / (3.0f * 21.0f);

__device__ __forceinline__ double block_reduce(double val) {
    __shared__ double smem[16];
    const int lane = threadIdx.x & 63;
    const int wid  = threadIdx.x >> 6;
    #pragma unroll
    for (int off = 32; off > 0; off >>= 1)
        val += __shfl_down(val, off, 64);
    if (lane == 0) smem[wid] = val;
    __syncthreads();
    if (wid == 0) {
        const int nw = blockDim.x >> 6;
        val = (lane < nw) ? smem[lane] : 0.0;
        #pragma unroll
        for (int off = 32; off > 0; off >>= 1)
            val += __shfl_down(val, off, 64);
    }
    return val;
}

__global__ __launch_bounds__(256) void pose_loss_kernel(
    const float* __restrict__ pose3d,      // (W+1, 3, 21)
    const float* __restrict__ bone_2d,     // (W, 2, 21)
    const float* __restrict__ lift_dirs,   // (W, 3, 20)
    const float* __restrict__ R_drone,     // (W, 3, 3)
    const float* __restrict__ C_drone,     // (W, 3, 1)
    const float* __restrict__ bone_len,    // (20,)
    const float* __restrict__ R_cam,       // (3,3)
    const int*   __restrict__ bc,          // (20,2)
    float* __restrict__ out,
    int W)
{
    const int tid = blockIdx.x * blockDim.x + threadIdx.x;
    float partial = 0.0f;

    if (tid < W * JN) {
        const int w = tid / JN;
        const int j = tid - w * JN;

        const float* Pw  = pose3d + (size_t)w * (3 * JN);   // frame w
        const float* Pw1 = Pw + 3 * JN;                      // frame w+1

        const float p1x = Pw1[j];
        const float p1y = Pw1[JN + j];
        const float p1z = Pw1[2 * JN + j];

        // ---------------- projection loss (frame w, joint j) ----------------
        {
            const float* Rd = R_drone + (size_t)w * 9;
            const float* Cd = C_drone + (size_t)w * 3;
            // M = R_cam @ R_drone[w]^T :  M[i][k] = sum_t Rcam[i][t] * Rd[k][t]
            float M[3][3];
            #pragma unroll
            for (int i = 0; i < 3; ++i) {
                const float rc0 = R_cam[i * 3 + 0];
                const float rc1 = R_cam[i * 3 + 1];
                const float rc2 = R_cam[i * 3 + 2];
                #pragma unroll
                for (int k = 0; k < 3; ++k) {
                    M[i][k] = rc0 * Rd[k * 3 + 0] + rc1 * Rd[k * 3 + 1] + rc2 * Rd[k * 3 + 2];
                }
            }
            const float rx = p1x - Cd[0];
            const float ry = p1y - Cd[1];
            const float rz = p1z - Cd[2];
            const float c0 = M[0][0] * rx + M[0][1] * ry + M[0][2] * rz;
            const float c1 = M[1][0] * rx + M[1][1] * ry + M[1][2] * rz;
            const float c2 = M[2][0] * rx + M[2][1] * ry + M[2][2] * rz;
            const float invz = 1.0f / c2;
            const float u = F_F * c0 * invz + PX_F;
            const float v = F_F * c1 * invz + PY_F;
            const float du = u - bone_2d[(size_t)w * (2 * JN) + j];
            const float dv = v - bone_2d[(size_t)w * (2 * JN) + JN + j];
            partial += WPROJ * (du * du + dv * dv);
        }

        // ---------------- lift + bone losses (bone j, j < 20) ----------------
        if (j < BN) {
            const int b0 = bc[2 * j];
            const int b1 = bc[2 * j + 1];

            // lift: frame w+1 bone vector direction
            {
                const float ax = Pw1[b0]          - Pw1[b1];
                const float ay = Pw1[JN + b0]     - Pw1[JN + b1];
                const float az = Pw1[2 * JN + b0] - Pw1[2 * JN + b1];
                const float inv = 1.0f / (sqrtf(ax * ax + ay * ay + az * az) + EPS_F);
                const float lx = lift_dirs[(size_t)w * (3 * BN) + j]          - ax * inv;
                const float ly = lift_dirs[(size_t)w * (3 * BN) + BN + j]     - ay * inv;
                const float lz = lift_dirs[(size_t)w * (3 * BN) + 2 * BN + j] - az * inv;
                partial += WLIFT * (lx * lx + ly * ly + lz * lz);
            }

            // bone: frame w (thread (W-1, j) additionally covers frame W)
            const float blj = bone_len[j];
            {
                const float bx = Pw[b0]          - Pw[b1];
                const float by = Pw[JN + b0]     - Pw[JN + b1];
                const float bz = Pw[2 * JN + b0] - Pw[2 * JN + b1];
                const float bl = bx * bx + by * by + bz * bz;
                const float e = blj - bl;
                partial += WBONE * (e * e);
            }
            if (w == W - 1) {  // frame W == Pw1 here
                const float bx = Pw1[b0]          - Pw1[b1];
                const float by = Pw1[JN + b0]     - Pw1[JN + b1];
                const float bz = Pw1[2 * JN + b0] - Pw1[2 * JN + b1];
                const float bl = bx * bx + by * by + bz * bz;
                const float e = blj - bl;
                partial += WBONE * (e * e);
            }
        }

        // ---------------- smoothness loss (t = w, w < W-1) ----------------
        if (w < W - 1) {
            const float* Pw2 = Pw + 2 * (3 * JN);  // frame w+2
            const float sx = Pw2[j]          - 2.0f * p1x + Pw[j];
            const float sy = Pw2[JN + j]     - 2.0f * p1y + Pw[JN + j];
            const float sz = Pw2[2 * JN + j] - 2.0f * p1z + Pw[2 * JN + j];
            partial += WSMOOTH * (sx * sx + sy * sy + sz * sz);
        }
    }

    const double bsum = block_reduce((double)partial);
    if (threadIdx.x == 0) atomicAdd(out, (float)bsum);
}

}  // namespace

extern "C" void kernel_launch(void* const* d_in, const int* in_sizes, int n_in,
                              void* d_out, int out_size, void* d_ws, size_t ws_size,
                              hipStream_t stream) {
    const float* pose3d    = (const float*)d_in[0];
    const float* bone_2d   = (const float*)d_in[1];
    const float* lift_dirs = (const float*)d_in[2];
    const float* R_drone   = (const float*)d_in[3];
    const float* C_drone   = (const float*)d_in[4];
    const float* bone_len  = (const float*)d_in[5];
    const float* R_cam     = (const float*)d_in[6];
    const int*   bc        = (const int*)d_in[7];
    float* out = (float*)d_out;

    const int W = in_sizes[3] / 9;  // R_drone is (W,3,3)

    hipMemsetAsync(out, 0, sizeof(float), stream);

    const int total = W * JN;
    const int block = 256;
    const int grid = (total + block - 1) / block;
    pose_loss_kernel<<<grid, block, 0, stream>>>(
        pose3d, bone_2d, lift_dirs, R_drone, C_drone, bone_len, R_cam, bc, out, W);
}

// Round 2
// 38.940 us; speedup vs baseline: 3.9083x; 3.9083x over previous
//
#include <hip/hip_runtime.h>

namespace {

constexpr int JN = 21;   // joints
constexpr int BN = 20;   // bones
constexpr float F_F  = 512.0f;
constexpr float PX_F = 512.0f;
constexpr float PY_F = 288.0f;
constexpr float EPS_F = 1e-8f;

// weights folded with per-loss divisors
constexpr float WPROJ   = 0.25f / (2.0f * 21.0f);
constexpr float WLIFT   = 0.25f / (3.0f * 21.0f);
constexpr float WBONE   = 0.25f / 20.0f;
constexpr float WSMOOTH = 0.25f / (3.0f * 21.0f);

constexpr int GRID = 2048;   // fixed grid; each block emits ONE partial to d_ws

__device__ __forceinline__ double block_reduce(double val) {
    __shared__ double smem[16];
    const int lane = threadIdx.x & 63;
    const int wid  = threadIdx.x >> 6;
    #pragma unroll
    for (int off = 32; off > 0; off >>= 1)
        val += __shfl_down(val, off, 64);
    if (lane == 0) smem[wid] = val;
    __syncthreads();
    if (wid == 0) {
        const int nw = blockDim.x >> 6;
        val = (lane < nw) ? smem[lane] : 0.0;
        #pragma unroll
        for (int off = 32; off > 0; off >>= 1)
            val += __shfl_down(val, off, 64);
    }
    return val;
}

__global__ __launch_bounds__(256) void pose_loss_kernel(
    const float* __restrict__ pose3d,      // (W+1, 3, 21)
    const float* __restrict__ bone_2d,     // (W, 2, 21)
    const float* __restrict__ lift_dirs,   // (W, 3, 20)
    const float* __restrict__ R_drone,     // (W, 3, 3)
    const float* __restrict__ C_drone,     // (W, 3, 1)
    const float* __restrict__ bone_len,    // (20,)
    const float* __restrict__ R_cam,       // (3,3)
    const int*   __restrict__ bc,          // (20,2)
    float* __restrict__ partials,          // (GRID,)
    int W)
{
    const int total  = W * JN;
    const int stride = gridDim.x * blockDim.x;
    float partial = 0.0f;

    for (int tid = blockIdx.x * blockDim.x + threadIdx.x; tid < total; tid += stride) {
        const int w = tid / JN;
        const int j = tid - w * JN;

        const float* Pw  = pose3d + (size_t)w * (3 * JN);   // frame w
        const float* Pw1 = Pw + 3 * JN;                      // frame w+1

        const float p1x = Pw1[j];
        const float p1y = Pw1[JN + j];
        const float p1z = Pw1[2 * JN + j];

        // ---------------- projection loss (frame w, joint j) ----------------
        {
            const float* Rd = R_drone + (size_t)w * 9;
            const float* Cd = C_drone + (size_t)w * 3;
            // M = R_cam @ R_drone[w]^T :  M[i][k] = sum_t Rcam[i][t] * Rd[k][t]
            float M[3][3];
            #pragma unroll
            for (int i = 0; i < 3; ++i) {
                const float rc0 = R_cam[i * 3 + 0];
                const float rc1 = R_cam[i * 3 + 1];
                const float rc2 = R_cam[i * 3 + 2];
                #pragma unroll
                for (int k = 0; k < 3; ++k) {
                    M[i][k] = rc0 * Rd[k * 3 + 0] + rc1 * Rd[k * 3 + 1] + rc2 * Rd[k * 3 + 2];
                }
            }
            const float rx = p1x - Cd[0];
            const float ry = p1y - Cd[1];
            const float rz = p1z - Cd[2];
            const float c0 = M[0][0] * rx + M[0][1] * ry + M[0][2] * rz;
            const float c1 = M[1][0] * rx + M[1][1] * ry + M[1][2] * rz;
            const float c2 = M[2][0] * rx + M[2][1] * ry + M[2][2] * rz;
            const float invz = 1.0f / c2;
            const float u = F_F * c0 * invz + PX_F;
            const float v = F_F * c1 * invz + PY_F;
            const float du = u - bone_2d[(size_t)w * (2 * JN) + j];
            const float dv = v - bone_2d[(size_t)w * (2 * JN) + JN + j];
            partial += WPROJ * (du * du + dv * dv);
        }

        // ---------------- lift + bone losses (bone j, j < 20) ----------------
        if (j < BN) {
            const int b0 = bc[2 * j];
            const int b1 = bc[2 * j + 1];

            // lift: frame w+1 bone vector direction
            {
                const float ax = Pw1[b0]          - Pw1[b1];
                const float ay = Pw1[JN + b0]     - Pw1[JN + b1];
                const float az = Pw1[2 * JN + b0] - Pw1[2 * JN + b1];
                const float inv = 1.0f / (sqrtf(ax * ax + ay * ay + az * az) + EPS_F);
                const float lx = lift_dirs[(size_t)w * (3 * BN) + j]          - ax * inv;
                const float ly = lift_dirs[(size_t)w * (3 * BN) + BN + j]     - ay * inv;
                const float lz = lift_dirs[(size_t)w * (3 * BN) + 2 * BN + j] - az * inv;
                partial += WLIFT * (lx * lx + ly * ly + lz * lz);
            }

            // bone: frame w (thread (W-1, j) additionally covers frame W)
            const float blj = bone_len[j];
            {
                const float bx = Pw[b0]          - Pw[b1];
                const float by = Pw[JN + b0]     - Pw[JN + b1];
                const float bz = Pw[2 * JN + b0] - Pw[2 * JN + b1];
                const float bl = bx * bx + by * by + bz * bz;
                const float e = blj - bl;
                partial += WBONE * (e * e);
            }
            if (w == W - 1) {  // frame W == Pw1 here
                const float bx = Pw1[b0]          - Pw1[b1];
                const float by = Pw1[JN + b0]     - Pw1[JN + b1];
                const float bz = Pw1[2 * JN + b0] - Pw1[2 * JN + b1];
                const float bl = bx * bx + by * by + bz * bz;
                const float e = blj - bl;
                partial += WBONE * (e * e);
            }
        }

        // ---------------- smoothness loss (t = w, w < W-1) ----------------
        if (w < W - 1) {
            const float* Pw2 = Pw + 2 * (3 * JN);  // frame w+2
            const float sx = Pw2[j]          - 2.0f * p1x + Pw[j];
            const float sy = Pw2[JN + j]     - 2.0f * p1y + Pw[JN + j];
            const float sz = Pw2[2 * JN + j] - 2.0f * p1z + Pw[2 * JN + j];
            partial += WSMOOTH * (sx * sx + sy * sy + sz * sz);
        }
    }

    const double bsum = block_reduce((double)partial);
    if (threadIdx.x == 0) partials[blockIdx.x] = (float)bsum;
}

__global__ __launch_bounds__(256) void final_reduce_kernel(
    const float* __restrict__ partials, float* __restrict__ out, int n)
{
    double v = 0.0;
    for (int i = threadIdx.x; i < n; i += blockDim.x)
        v += (double)partials[i];
    v = block_reduce(v);
    if (threadIdx.x == 0) out[0] = (float)v;
}

}  // namespace

extern "C" void kernel_launch(void* const* d_in, const int* in_sizes, int n_in,
                              void* d_out, int out_size, void* d_ws, size_t ws_size,
                              hipStream_t stream) {
    const float* pose3d    = (const float*)d_in[0];
    const float* bone_2d   = (const float*)d_in[1];
    const float* lift_dirs = (const float*)d_in[2];
    const float* R_drone   = (const float*)d_in[3];
    const float* C_drone   = (const float*)d_in[4];
    const float* bone_len  = (const float*)d_in[5];
    const float* R_cam     = (const float*)d_in[6];
    const int*   bc        = (const int*)d_in[7];
    float* out = (float*)d_out;
    float* partials = (float*)d_ws;

    const int W = in_sizes[3] / 9;  // R_drone is (W,3,3)

    int grid = GRID;
    if ((size_t)grid * sizeof(float) > ws_size) grid = (int)(ws_size / sizeof(float));

    pose_loss_kernel<<<grid, 256, 0, stream>>>(
        pose3d, bone_2d, lift_dirs, R_drone, C_drone, bone_len, R_cam, bc, partials, W);
    final_reduce_kernel<<<1, 256, 0, stream>>>(partials, out, grid);
}

// Round 3
// 28.936 us; speedup vs baseline: 5.2594x; 1.3457x over previous
//
#include <hip/hip_runtime.h>

namespace {

constexpr int JN = 21;   // joints
constexpr int BN = 20;   // bones
constexpr int FR = 64;   // frames per block
constexpr float F_F  = 512.0f;
constexpr float PX_F = 512.0f;
constexpr float PY_F = 288.0f;
constexpr float EPS_F = 1e-8f;

// weights folded with per-loss divisors
constexpr float WPROJ   = 0.25f / (2.0f * 21.0f);
constexpr float WLIFT   = 0.25f / (3.0f * 21.0f);
constexpr float WBONE   = 0.25f / 20.0f;
constexpr float WSMOOTH = 0.25f / (3.0f * 21.0f);

__device__ __forceinline__ double block_reduce(double val) {
    __shared__ double smem[16];
    const int lane = threadIdx.x & 63;
    const int wid  = threadIdx.x >> 6;
    #pragma unroll
    for (int off = 32; off > 0; off >>= 1)
        val += __shfl_down(val, off, 64);
    if (lane == 0) smem[wid] = val;
    __syncthreads();
    if (wid == 0) {
        const int nw = blockDim.x >> 6;
        val = (lane < nw) ? smem[lane] : 0.0;
        #pragma unroll
        for (int off = 32; off > 0; off >>= 1)
            val += __shfl_down(val, off, 64);
    }
    return val;
}

__global__ __launch_bounds__(256) void pose_loss_kernel(
    const float* __restrict__ pose3d,      // (W+1, 3, 21)
    const float* __restrict__ bone_2d,     // (W, 2, 21)
    const float* __restrict__ lift_dirs,   // (W, 3, 20)
    const float* __restrict__ R_drone,     // (W, 3, 3)
    const float* __restrict__ C_drone,     // (W, 3, 1)
    const float* __restrict__ bone_len,    // (20,)
    const float* __restrict__ R_cam,       // (3,3)
    const int*   __restrict__ bc,          // (20,2)
    float* __restrict__ partials,          // (gridDim.x,)
    int W)
{
    __shared__ float s_pose[(FR + 2) * 63];  // frames [w0, w0+FR+2)
    __shared__ float s_M[FR * 9];            // R_drone chunk, overwritten by M = R_cam @ Rd^T
    __shared__ float s_MC[FR * 3];           // C chunk, overwritten by M @ C

    const int tid = threadIdx.x;
    const int w0  = blockIdx.x * FR;

    // ---------- stage (fully coalesced, contiguous chunks) ----------
    const int nPoseF = min(FR + 2, W + 1 - w0);
    const int nP = nPoseF * 63;
    const float* gp = pose3d + (size_t)w0 * 63;
    for (int i = tid; i < nP; i += 256) s_pose[i] = gp[i];

    const float* gr = R_drone + (size_t)w0 * 9;
    for (int i = tid; i < FR * 9; i += 256) s_M[i] = gr[i];

    const float* gc = C_drone + (size_t)w0 * 3;
    for (int i = tid; i < FR * 3; i += 256) s_MC[i] = gc[i];

    __syncthreads();

    // ---------- per-frame precompute: M = R_cam @ Rd^T, MC = M @ C ----------
    if (tid < FR) {
        float Rd[9];
        #pragma unroll
        for (int k = 0; k < 9; ++k) Rd[k] = s_M[tid * 9 + k];
        float rc[9];
        #pragma unroll
        for (int k = 0; k < 9; ++k) rc[k] = R_cam[k];   // uniform -> broadcast
        float M[9];
        #pragma unroll
        for (int i = 0; i < 3; ++i)
            #pragma unroll
            for (int k = 0; k < 3; ++k)
                M[i * 3 + k] = rc[i * 3 + 0] * Rd[k * 3 + 0]
                             + rc[i * 3 + 1] * Rd[k * 3 + 1]
                             + rc[i * 3 + 2] * Rd[k * 3 + 2];
        float C0 = s_MC[tid * 3 + 0], C1 = s_MC[tid * 3 + 1], C2 = s_MC[tid * 3 + 2];
        #pragma unroll
        for (int k = 0; k < 9; ++k) s_M[tid * 9 + k] = M[k];
        #pragma unroll
        for (int i = 0; i < 3; ++i)
            s_MC[tid * 3 + i] = M[i * 3 + 0] * C0 + M[i * 3 + 1] * C1 + M[i * 3 + 2] * C2;
    }
    __syncthreads();

    // ---------- compute ----------
    float partial = 0.0f;
    for (int idx = tid; idx < FR * JN; idx += 256) {
        const int wl = idx / JN;
        const int j  = idx - wl * JN;
        const int w  = w0 + wl;

        const float* P1 = s_pose + (wl + 1) * 63;   // frame w+1
        const float p1x = P1[j];
        const float p1y = P1[JN + j];
        const float p1z = P1[2 * JN + j];

        // projection loss
        {
            const float* M  = s_M  + wl * 9;
            const float* MC = s_MC + wl * 3;
            const float c0 = M[0] * p1x + M[1] * p1y + M[2] * p1z - MC[0];
            const float c1 = M[3] * p1x + M[4] * p1y + M[5] * p1z - MC[1];
            const float c2 = M[6] * p1x + M[7] * p1y + M[8] * p1z - MC[2];
            const float invz = 1.0f / c2;
            const float u = F_F * c0 * invz + PX_F;
            const float v = F_F * c1 * invz + PY_F;
            const float du = u - bone_2d[(size_t)w * (2 * JN) + j];
            const float dv = v - bone_2d[(size_t)w * (2 * JN) + JN + j];
            partial += WPROJ * (du * du + dv * dv);
        }

        // lift + bone
        if (j < BN) {
            const int b0 = bc[2 * j];
            const int b1 = bc[2 * j + 1];
            {
                const float ax = P1[b0]          - P1[b1];
                const float ay = P1[JN + b0]     - P1[JN + b1];
                const float az = P1[2 * JN + b0] - P1[2 * JN + b1];
                const float inv = 1.0f / (sqrtf(ax * ax + ay * ay + az * az) + EPS_F);
                const float lx = lift_dirs[(size_t)w * (3 * BN) + j]          - ax * inv;
                const float ly = lift_dirs[(size_t)w * (3 * BN) + BN + j]     - ay * inv;
                const float lz = lift_dirs[(size_t)w * (3 * BN) + 2 * BN + j] - az * inv;
                partial += WLIFT * (lx * lx + ly * ly + lz * lz);
            }
            const float blj = bone_len[j];
            {
                const float* P0 = s_pose + wl * 63;          // frame w
                const float bx = P0[b0]          - P0[b1];
                const float by = P0[JN + b0]     - P0[JN + b1];
                const float bz = P0[2 * JN + b0] - P0[2 * JN + b1];
                const float bl = bx * bx + by * by + bz * bz;
                const float e = blj - bl;
                partial += WBONE * (e * e);
            }
            if (w == W - 1) {                                // frame W == P1 here
                const float bx = P1[b0]          - P1[b1];
                const float by = P1[JN + b0]     - P1[JN + b1];
                const float bz = P1[2 * JN + b0] - P1[2 * JN + b1];
                const float bl = bx * bx + by * by + bz * bz;
                const float e = blj - bl;
                partial += WBONE * (e * e);
            }
        }

        // smoothness (t = w)
        if (w < W - 1) {
            const float* P0 = s_pose + wl * 63;
            const float* P2 = s_pose + (wl + 2) * 63;
            const float sx = P2[j]          - 2.0f * p1x + P0[j];
            const float sy = P2[JN + j]     - 2.0f * p1y + P0[JN + j];
            const float sz = P2[2 * JN + j] - 2.0f * p1z + P0[2 * JN + j];
            partial += WSMOOTH * (sx * sx + sy * sy + sz * sz);
        }
    }

    const double bsum = block_reduce((double)partial);
    if (tid == 0) partials[blockIdx.x] = (float)bsum;
}

__global__ __launch_bounds__(256) void final_reduce_kernel(
    const float* __restrict__ partials, float* __restrict__ out, int n)
{
    double v = 0.0;
    for (int i = threadIdx.x; i < n; i += blockDim.x)
        v += (double)partials[i];
    v = block_reduce(v);
    if (threadIdx.x == 0) out[0] = (float)v;
}

}  // namespace

extern "C" void kernel_launch(void* const* d_in, const int* in_sizes, int n_in,
                              void* d_out, int out_size, void* d_ws, size_t ws_size,
                              hipStream_t stream) {
    const float* pose3d    = (const float*)d_in[0];
    const float* bone_2d   = (const float*)d_in[1];
    const float* lift_dirs = (const float*)d_in[2];
    const float* R_drone   = (const float*)d_in[3];
    const float* C_drone   = (const float*)d_in[4];
    const float* bone_len  = (const float*)d_in[5];
    const float* R_cam     = (const float*)d_in[6];
    const int*   bc        = (const int*)d_in[7];
    float* out = (float*)d_out;
    float* partials = (float*)d_ws;

    const int W = in_sizes[3] / 9;       // R_drone is (W,3,3)
    const int grid = (W + FR - 1) / FR;  // 2048 for W=131072

    pose_loss_kernel<<<grid, 256, 0, stream>>>(
        pose3d, bone_2d, lift_dirs, R_drone, C_drone, bone_len, R_cam, bc, partials, W);
    final_reduce_kernel<<<1, 256, 0, stream>>>(partials, out, grid);
}